// Round 3
// baseline (195.273 us; speedup 1.0000x reference)
//
#include <hip/hip_runtime.h>
#include <hip/hip_fp16.h>

// ShiftDecoderNet fused kernel for MI355X (gfx950).
// R3: runtime dtype dispatch. R1/R2 NaN'd independent of barriers; only viable
// NaN source is reading f32 buffers as packed bf16 (random low-mantissa bits
// -> bf16-NaN payloads at p~2^-9). a_bits is exactly {0.0,1.0}: as f32, every
// dword is 0x0 or 0x3F800000 (low half 0x0000); as packed bf16, low half is
// 0x3F80 w.p. 1/2. Ballot over 64 words decides; wave-uniform template branch.
//
// Block = 256 threads = 4 waves; wave w owns 16 rows (band-local LDS use).
// GEMMs: mfma_f32_16x16x32_bf16.  A-frag: m=lane&15, k=(lane>>4)*8+j.
// B-frag from row-major W[out][in].  C/D: col=lane&15, row=(lane>>4)*4+reg.

typedef short s8v __attribute__((ext_vector_type(8)));   // 8 bf16 payloads
typedef float f4v __attribute__((ext_vector_type(4)));

#define HPAD 264   // 256 + 8: row stride 528B breaks pow2 bank conflicts
#define PPAD 68    // 64 + 4 f32 pad

__device__ __forceinline__ float b2f(unsigned short u) {
    union { unsigned int i; float f; } v; v.i = ((unsigned int)u) << 16; return v.f;
}
__device__ __forceinline__ unsigned short f2b(float f) {
    union { float f; unsigned int i; } v; v.f = f;
    return (unsigned short)((v.i + 0x7fffu + ((v.i >> 16) & 1u)) >> 16);  // RNE
}
__device__ __forceinline__ int h2i(__half2 h) { union { __half2 h; int i; } u; u.h = h; return u.i; }
__device__ __forceinline__ __half2 i2h(int i) { union { __half2 h; int i; } u; u.i = i; return u.h; }

// 8 contiguous elements as bf16 payloads (16B-aligned in either dtype)
template<bool BF16>
__device__ __forceinline__ s8v load8(const void* p, int idx) {
    if constexpr (BF16) {
        return *(const s8v*)((const unsigned short*)p + idx);
    } else {
        const float* f = (const float*)p + idx;
        f4v a = *(const f4v*)f;
        f4v b = *(const f4v*)(f + 4);
        s8v r;
#pragma unroll
        for (int i = 0; i < 4; ++i) { r[i] = (short)f2b(a[i]); r[4 + i] = (short)f2b(b[i]); }
        return r;
    }
}
template<bool BF16>
__device__ __forceinline__ float loadS(const void* p, int idx) {
    if constexpr (BF16) return b2f(((const unsigned short*)p)[idx]);
    else return ((const float*)p)[idx];
}
template<bool BF16>
__device__ __forceinline__ void storeO(void* p, int idx, float v) {
    if constexpr (BF16) ((unsigned short*)p)[idx] = f2b(v);
    else ((float*)p)[idx] = v;
}

template<bool BF16>
__device__ __forceinline__ void pipeline(
    const void* a_bits, const void* shifts,
    const void* W1, const void* b1, const void* g1, const void* be1,
    const void* W2, const void* b2, const void* g2, const void* be2,
    const void* W3, const void* b3, void* out,
    short* Hs, float* Ps)
{
    const int tid = threadIdx.x;
    const int w = tid >> 6;
    const int l = tid & 63;
    const int q = l >> 4;
    const int c = l & 15;
    const int rb = w << 4;
    const int grow0 = (int)blockIdx.x << 6;

    // ===== GEMM1: [16x64] @ W1^T -> [16x256], +b1, LN, ReLU =====
    f4v acc1[16];
#pragma unroll
    for (int nt = 0; nt < 16; ++nt) acc1[nt] = (f4v){0.f, 0.f, 0.f, 0.f};

    const s8v xa0 = load8<BF16>(shifts, (grow0 + rb + c) * 64 + q * 8);
    const s8v xa1 = load8<BF16>(shifts, (grow0 + rb + c) * 64 + 32 + q * 8);
#pragma unroll
    for (int nt = 0; nt < 16; ++nt) {
        s8v wb0 = load8<BF16>(W1, (nt * 16 + c) * 64 + q * 8);
        s8v wb1 = load8<BF16>(W1, (nt * 16 + c) * 64 + 32 + q * 8);
        acc1[nt] = __builtin_amdgcn_mfma_f32_16x16x32_bf16(xa0, wb0, acc1[nt], 0, 0, 0);
        acc1[nt] = __builtin_amdgcn_mfma_f32_16x16x32_bf16(xa1, wb1, acc1[nt], 0, 0, 0);
    }
    {
        float s[4] = {0, 0, 0, 0}, ss[4] = {0, 0, 0, 0};
#pragma unroll
        for (int nt = 0; nt < 16; ++nt) {
            float bias = loadS<BF16>(b1, nt * 16 + c);
#pragma unroll
            for (int r = 0; r < 4; ++r) {
                float v = acc1[nt][r] + bias;
                acc1[nt][r] = v;
                s[r] += v; ss[r] += v * v;
            }
        }
#pragma unroll
        for (int m = 1; m <= 8; m <<= 1)
#pragma unroll
            for (int r = 0; r < 4; ++r) {
                s[r]  += __shfl_xor(s[r],  m, 64);
                ss[r] += __shfl_xor(ss[r], m, 64);
            }
#pragma unroll
        for (int r = 0; r < 4; ++r) {
            float mean = s[r] * (1.0f / 256.0f);
            float var  = fmaxf(ss[r] * (1.0f / 256.0f) - mean * mean, 0.0f);
            s[r] = mean; ss[r] = rsqrtf(var + 1e-5f);
        }
#pragma unroll
        for (int nt = 0; nt < 16; ++nt) {
            float gg = loadS<BF16>(g1, nt * 16 + c);
            float bb = loadS<BF16>(be1, nt * 16 + c);
#pragma unroll
            for (int r = 0; r < 4; ++r) {
                float y = (acc1[nt][r] - s[r]) * ss[r] * gg + bb;
                Hs[(rb + q * 4 + r) * HPAD + nt * 16 + c] = (short)f2b(fmaxf(y, 0.0f));
            }
        }
    }
    __syncthreads();

    // ===== GEMM2: [16x256] @ W2^T -> [16x256], +b2, LN, ReLU =====
    f4v acc2[16];
#pragma unroll
    for (int nt = 0; nt < 16; ++nt) acc2[nt] = (f4v){0.f, 0.f, 0.f, 0.f};
#pragma unroll
    for (int ks = 0; ks < 8; ++ks) {
        s8v af = *(const s8v*)&Hs[(rb + c) * HPAD + ks * 32 + q * 8];
#pragma unroll
        for (int nt = 0; nt < 16; ++nt) {
            s8v bf_ = load8<BF16>(W2, (nt * 16 + c) * 256 + ks * 32 + q * 8);
            acc2[nt] = __builtin_amdgcn_mfma_f32_16x16x32_bf16(af, bf_, acc2[nt], 0, 0, 0);
        }
    }
    {
        float s[4] = {0, 0, 0, 0}, ss[4] = {0, 0, 0, 0};
#pragma unroll
        for (int nt = 0; nt < 16; ++nt) {
            float bias = loadS<BF16>(b2, nt * 16 + c);
#pragma unroll
            for (int r = 0; r < 4; ++r) {
                float v = acc2[nt][r] + bias;
                acc2[nt][r] = v;
                s[r] += v; ss[r] += v * v;
            }
        }
#pragma unroll
        for (int m = 1; m <= 8; m <<= 1)
#pragma unroll
            for (int r = 0; r < 4; ++r) {
                s[r]  += __shfl_xor(s[r],  m, 64);
                ss[r] += __shfl_xor(ss[r], m, 64);
            }
#pragma unroll
        for (int r = 0; r < 4; ++r) {
            float mean = s[r] * (1.0f / 256.0f);
            float var  = fmaxf(ss[r] * (1.0f / 256.0f) - mean * mean, 0.0f);
            s[r] = mean; ss[r] = rsqrtf(var + 1e-5f);
        }
        __syncthreads();
#pragma unroll
        for (int nt = 0; nt < 16; ++nt) {
            float gg = loadS<BF16>(g2, nt * 16 + c);
            float bb = loadS<BF16>(be2, nt * 16 + c);
#pragma unroll
            for (int r = 0; r < 4; ++r) {
                float y = (acc2[nt][r] - s[r]) * ss[r] * gg + bb;
                Hs[(rb + q * 4 + r) * HPAD + nt * 16 + c] = (short)f2b(fmaxf(y, 0.0f));
            }
        }
    }
    __syncthreads();

    // ===== GEMM3: [16x256] @ W3^T -> [16x64], +b3, softmax =====
    f4v acc3[4];
#pragma unroll
    for (int nt = 0; nt < 4; ++nt) acc3[nt] = (f4v){0.f, 0.f, 0.f, 0.f};
#pragma unroll
    for (int ks = 0; ks < 8; ++ks) {
        s8v af = *(const s8v*)&Hs[(rb + c) * HPAD + ks * 32 + q * 8];
#pragma unroll
        for (int nt = 0; nt < 4; ++nt) {
            s8v bf_ = load8<BF16>(W3, (nt * 16 + c) * 256 + ks * 32 + q * 8);
            acc3[nt] = __builtin_amdgcn_mfma_f32_16x16x32_bf16(af, bf_, acc3[nt], 0, 0, 0);
        }
    }
    {
        float mx[4] = {-1e30f, -1e30f, -1e30f, -1e30f};
#pragma unroll
        for (int nt = 0; nt < 4; ++nt) {
            float bias = loadS<BF16>(b3, nt * 16 + c);
#pragma unroll
            for (int r = 0; r < 4; ++r) {
                float v = acc3[nt][r] + bias;
                acc3[nt][r] = v;
                mx[r] = fmaxf(mx[r], v);
            }
        }
#pragma unroll
        for (int m = 1; m <= 8; m <<= 1)
#pragma unroll
            for (int r = 0; r < 4; ++r)
                mx[r] = fmaxf(mx[r], __shfl_xor(mx[r], m, 64));
        float sum[4] = {0, 0, 0, 0};
#pragma unroll
        for (int nt = 0; nt < 4; ++nt)
#pragma unroll
            for (int r = 0; r < 4; ++r) {
                float e = __expf(acc3[nt][r] - mx[r]);
                acc3[nt][r] = e;
                sum[r] += e;
            }
#pragma unroll
        for (int m = 1; m <= 8; m <<= 1)
#pragma unroll
            for (int r = 0; r < 4; ++r)
                sum[r] += __shfl_xor(sum[r], m, 64);
#pragma unroll
        for (int r = 0; r < 4; ++r) sum[r] = 1.0f / sum[r];
#pragma unroll
        for (int nt = 0; nt < 4; ++nt)
#pragma unroll
            for (int r = 0; r < 4; ++r)
                Ps[(rb + q * 4 + r) * PPAD + nt * 16 + c] = acc3[nt][r] * sum[r];
    }
    __syncthreads();

    // ===== Toeplitz causal shift-sum: out[m,i] = sum_{s<=i} p[m,s]*a[m,i-s] =====
#pragma unroll 1
    for (int j = 0; j < 8; ++j) {
        const int m0 = rb + j, m1 = rb + j + 8;
        __half2 pph = __floats2half2_rn(Ps[m0 * PPAD + l], Ps[m1 * PPAD + l]);
        const int ppi = h2i(pph);
        __half2 aah = __floats2half2_rn(loadS<BF16>(a_bits, (grow0 + m0) * 64 + l),
                                        loadS<BF16>(a_bits, (grow0 + m1) * 64 + l));
        const int aai = h2i(aah);
        __half2 acc = __float2half2_rn(0.0f);
#pragma unroll
        for (int s = 0; s < 64; ++s) {
            const int spi = __builtin_amdgcn_readlane(ppi, s);
            const int idx = l - s;
            const int av = __shfl(aai, idx < 0 ? 0 : idx, 64);
            if (idx >= 0)
                acc = __hfma2(i2h(spi), i2h(av), acc);
        }
        storeO<BF16>(out, (grow0 + m0) * 64 + l, __low2float(acc));
        storeO<BF16>(out, (grow0 + m1) * 64 + l, __high2float(acc));
    }
}

__global__ __launch_bounds__(256, 2) void shiftdec_kernel(
    const void* __restrict__ a_bits, const void* __restrict__ shifts,
    const void* __restrict__ W1, const void* __restrict__ b1,
    const void* __restrict__ g1, const void* __restrict__ be1,
    const void* __restrict__ W2, const void* __restrict__ b2,
    const void* __restrict__ g2, const void* __restrict__ be2,
    const void* __restrict__ W3, const void* __restrict__ b3,
    void* __restrict__ out)
{
    __shared__ __align__(16) short Hs[64 * HPAD];   // 33792 B
    __shared__ __align__(16) float Ps[64 * PPAD];   // 17408 B

    // dtype probe: a_bits is exactly {0.0,1.0}. f32 dwords: {0x0,0x3F800000}
    // (low half always 0). packed-bf16 dwords: low half 0x3F80 w.p. 1/2.
    const int l = threadIdx.x & 63;
    unsigned int wv = ((const unsigned int*)a_bits)[l];
    bool isbf = __ballot((wv & 0xffffu) == 0x3f80u) != 0ULL;

    if (isbf)
        pipeline<true>(a_bits, shifts, W1, b1, g1, be1, W2, b2, g2, be2, W3, b3, out, Hs, Ps);
    else
        pipeline<false>(a_bits, shifts, W1, b1, g1, be1, W2, b2, g2, be2, W3, b3, out, Hs, Ps);
}

extern "C" void kernel_launch(void* const* d_in, const int* in_sizes, int n_in,
                              void* d_out, int out_size, void* d_ws, size_t ws_size,
                              hipStream_t stream) {
    const int B = in_sizes[0] / 64;      // rows (32768)
    const int grid = B / 64;             // 64 rows per block
    hipLaunchKernelGGL(shiftdec_kernel, dim3(grid), dim3(256), 0, stream,
                       d_in[0], d_in[1], d_in[2], d_in[3], d_in[4], d_in[5],
                       d_in[6], d_in[7], d_in[8], d_in[9], d_in[10], d_in[11],
                       d_out);
}

// Round 4
// 144.581 us; speedup vs baseline: 1.3506x; 1.3506x over previous
//
#include <hip/hip_runtime.h>
#include <hip/hip_fp16.h>

// ShiftDecoderNet fused kernel for MI355X (gfx950).  R4.
// R3 passed (f32 path; WRITE=8MB proves f32 buffers). 140us with all pipes idle.
// R4: (1) pre-convert+pre-swizzle weights to bf16 MFMA-frag order in d_ws
//     (kills ~7.7K f2b VALU insts/wave + makes weight loads 16B/lane coalesced),
//     (2) Toeplitz via DPP wave_shr:1 instead of ds_bpermute (frees DS pipe),
//     (3) Ps overlaid on Hs (barrier-separated), LDS 51->34 KB.
//
// Block = 256 threads = 4 waves; wave w owns 16 rows (band-local LDS).
// GEMMs: mfma_f32_16x16x32_bf16.  A-frag: m=lane&15, k=(lane>>4)*8+j.
// C/D: col=lane&15, row=(lane>>4)*4+reg  (verified layouts).

typedef short s8v __attribute__((ext_vector_type(8)));   // 8 bf16 payloads
typedef float f4v __attribute__((ext_vector_type(4)));

#define HPAD 264   // short elements; row stride 528B breaks pow2 bank conflicts
#define PPAD 68    // float elements

// d_ws layout (bf16 elements)
#define OFF_W1F 0        // 16nt x 2kc x 64lane x 8  = 16384
#define OFF_W2F 16384    // 16nt x 8kc x 64lane x 8  = 65536
#define OFF_W3F 81920    //  4nt x 8kc x 64lane x 8  = 16384
#define OFF_B1  98304
#define OFF_G1  98560
#define OFF_BE1 98816
#define OFF_B2  99072
#define OFF_G2  99328
#define OFF_BE2 99584
#define OFF_B3  99840    // 64

__device__ __forceinline__ float b2f(unsigned short u) {
    union { unsigned int i; float f; } v; v.i = ((unsigned int)u) << 16; return v.f;
}
__device__ __forceinline__ unsigned short f2b(float f) {
    union { float f; unsigned int i; } v; v.f = f;
    return (unsigned short)((v.i + 0x7fffu + ((v.i >> 16) & 1u)) >> 16);  // RNE
}
__device__ __forceinline__ int h2i(__half2 h) { union { __half2 h; int i; } u; u.h = h; return u.i; }
__device__ __forceinline__ __half2 i2h(int i) { union { __half2 h; int i; } u; u.i = i; return u.h; }

__device__ __forceinline__ bool probe_bf16(const void* a_bits) {
    // a_bits is exactly {0.0,1.0}. f32 dwords: {0x0,0x3F800000} (low half 0).
    // packed-bf16 dwords: low half 0x3F80 w.p. 1/2 per word.
    unsigned int wv = ((const unsigned int*)a_bits)[threadIdx.x & 63];
    return __ballot((wv & 0xffffu) == 0x3f80u) != 0ULL;
}

// ============ kernel 0: convert + swizzle weights into d_ws (bf16) ============
__global__ __launch_bounds__(256) void convert_kernel(
    const void* __restrict__ a_probe,
    const void* __restrict__ W1, const void* __restrict__ W2, const void* __restrict__ W3,
    const void* __restrict__ b1, const void* __restrict__ g1, const void* __restrict__ be1,
    const void* __restrict__ b2, const void* __restrict__ g2, const void* __restrict__ be2,
    const void* __restrict__ b3,
    unsigned short* __restrict__ ws)
{
    const bool isbf = probe_bf16(a_probe);
    const int t = blockIdx.x * 256 + threadIdx.x;

    if (t < 12288) {            // weight 8-element chunks, frag order
        const void* W; int K, idx, dstbase;
        if (t < 2048)       { idx = t;         W = W1; K = 64;  dstbase = OFF_W1F + idx * 8; }
        else if (t < 10240) { idx = t - 2048;  W = W2; K = 256; dstbase = OFF_W2F + idx * 8; }
        else                { idx = t - 10240; W = W3; K = 256; dstbase = OFF_W3F + idx * 8; }
        int nt, kc, lane;
        if (t < 2048) { nt = idx >> 7; kc = (idx >> 6) & 1; lane = idx & 63; }
        else          { nt = idx >> 9; kc = (idx >> 6) & 7; lane = idx & 63; }
        const int row = nt * 16 + (lane & 15);
        const int col = kc * 32 + (lane >> 4) * 8;
        const int src = row * K + col;
        s8v o;
        if (isbf) {
            o = *(const s8v*)((const unsigned short*)W + src);
        } else {
            const float* f = (const float*)W + src;
#pragma unroll
            for (int j = 0; j < 8; ++j) o[j] = (short)f2b(f[j]);
        }
        *(s8v*)(ws + dstbase) = o;
    } else if (t < 12488) {     // bias/gamma/beta 8-element chunks (no straddle)
        const int v = t - 12288;
        const void* srcp; int base, off;
        if (v < 32)       { srcp = b1;  base = OFF_B1;  off = v * 8; }
        else if (v < 64)  { srcp = g1;  base = OFF_G1;  off = (v - 32) * 8; }
        else if (v < 96)  { srcp = be1; base = OFF_BE1; off = (v - 64) * 8; }
        else if (v < 128) { srcp = b2;  base = OFF_B2;  off = (v - 96) * 8; }
        else if (v < 160) { srcp = g2;  base = OFF_G2;  off = (v - 128) * 8; }
        else if (v < 192) { srcp = be2; base = OFF_BE2; off = (v - 160) * 8; }
        else              { srcp = b3;  base = OFF_B3;  off = (v - 192) * 8; }
#pragma unroll
        for (int j = 0; j < 8; ++j)
            ws[base + off + j] = isbf ? ((const unsigned short*)srcp)[off + j]
                                      : f2b(((const float*)srcp)[off + j]);
    }
}

// ======================= main fused pipeline ==================================
template<bool BF16>
__device__ __forceinline__ float loadS(const void* p, int idx) {
    if constexpr (BF16) return b2f(((const unsigned short*)p)[idx]);
    else return ((const float*)p)[idx];
}
template<bool BF16>
__device__ __forceinline__ s8v loadA8(const void* p, int idx) {   // activations
    if constexpr (BF16) {
        return *(const s8v*)((const unsigned short*)p + idx);
    } else {
        const float* f = (const float*)p + idx;
        f4v a = *(const f4v*)f;
        f4v b = *(const f4v*)(f + 4);
        s8v r;
#pragma unroll
        for (int i = 0; i < 4; ++i) { r[i] = (short)f2b(a[i]); r[4 + i] = (short)f2b(b[i]); }
        return r;
    }
}
template<bool BF16>
__device__ __forceinline__ void storeO(void* p, int idx, float v) {
    if constexpr (BF16) ((unsigned short*)p)[idx] = f2b(v);
    else ((float*)p)[idx] = v;
}

template<bool BF16>
__device__ __forceinline__ void pipeline(
    const void* a_bits, const void* shifts, const unsigned short* ws, void* out,
    short* Hs, float* Ps)
{
    const int tid = threadIdx.x;
    const int w = tid >> 6;
    const int l = tid & 63;
    const int q = l >> 4;
    const int c = l & 15;
    const int rb = w << 4;
    const int grow0 = (int)blockIdx.x << 6;

    // ===== GEMM1: [16x64] @ W1^T -> [16x256], +b1, LN, ReLU =====
    f4v acc1[16];
#pragma unroll
    for (int nt = 0; nt < 16; ++nt) acc1[nt] = (f4v){0.f, 0.f, 0.f, 0.f};

    const s8v xa0 = loadA8<BF16>(shifts, (grow0 + rb + c) * 64 + q * 8);
    const s8v xa1 = loadA8<BF16>(shifts, (grow0 + rb + c) * 64 + 32 + q * 8);
#pragma unroll
    for (int nt = 0; nt < 16; ++nt) {
        s8v wb0 = *(const s8v*)(ws + OFF_W1F + ((nt * 2 + 0) * 64 + l) * 8);
        s8v wb1 = *(const s8v*)(ws + OFF_W1F + ((nt * 2 + 1) * 64 + l) * 8);
        acc1[nt] = __builtin_amdgcn_mfma_f32_16x16x32_bf16(xa0, wb0, acc1[nt], 0, 0, 0);
        acc1[nt] = __builtin_amdgcn_mfma_f32_16x16x32_bf16(xa1, wb1, acc1[nt], 0, 0, 0);
    }
    {
        float s[4] = {0, 0, 0, 0}, ss[4] = {0, 0, 0, 0};
#pragma unroll
        for (int nt = 0; nt < 16; ++nt) {
            float bias = b2f(ws[OFF_B1 + nt * 16 + c]);
#pragma unroll
            for (int r = 0; r < 4; ++r) {
                float v = acc1[nt][r] + bias;
                acc1[nt][r] = v;
                s[r] += v; ss[r] += v * v;
            }
        }
#pragma unroll
        for (int m = 1; m <= 8; m <<= 1)
#pragma unroll
            for (int r = 0; r < 4; ++r) {
                s[r]  += __shfl_xor(s[r],  m, 64);
                ss[r] += __shfl_xor(ss[r], m, 64);
            }
#pragma unroll
        for (int r = 0; r < 4; ++r) {
            float mean = s[r] * (1.0f / 256.0f);
            float var  = fmaxf(ss[r] * (1.0f / 256.0f) - mean * mean, 0.0f);
            s[r] = mean; ss[r] = rsqrtf(var + 1e-5f);
        }
#pragma unroll
        for (int nt = 0; nt < 16; ++nt) {
            float gg = b2f(ws[OFF_G1 + nt * 16 + c]);
            float bb = b2f(ws[OFF_BE1 + nt * 16 + c]);
#pragma unroll
            for (int r = 0; r < 4; ++r) {
                float y = (acc1[nt][r] - s[r]) * ss[r] * gg + bb;
                Hs[(rb + q * 4 + r) * HPAD + nt * 16 + c] = (short)f2b(fmaxf(y, 0.0f));
            }
        }
    }
    __syncthreads();

    // ===== GEMM2: [16x256] @ W2^T -> [16x256], +b2, LN, ReLU =====
    f4v acc2[16];
#pragma unroll
    for (int nt = 0; nt < 16; ++nt) acc2[nt] = (f4v){0.f, 0.f, 0.f, 0.f};
#pragma unroll
    for (int ks = 0; ks < 8; ++ks) {
        s8v af = *(const s8v*)&Hs[(rb + c) * HPAD + ks * 32 + q * 8];
#pragma unroll
        for (int nt = 0; nt < 16; ++nt) {
            s8v bf_ = *(const s8v*)(ws + OFF_W2F + ((nt * 8 + ks) * 64 + l) * 8);
            acc2[nt] = __builtin_amdgcn_mfma_f32_16x16x32_bf16(af, bf_, acc2[nt], 0, 0, 0);
        }
    }
    {
        float s[4] = {0, 0, 0, 0}, ss[4] = {0, 0, 0, 0};
#pragma unroll
        for (int nt = 0; nt < 16; ++nt) {
            float bias = b2f(ws[OFF_B2 + nt * 16 + c]);
#pragma unroll
            for (int r = 0; r < 4; ++r) {
                float v = acc2[nt][r] + bias;
                acc2[nt][r] = v;
                s[r] += v; ss[r] += v * v;
            }
        }
#pragma unroll
        for (int m = 1; m <= 8; m <<= 1)
#pragma unroll
            for (int r = 0; r < 4; ++r) {
                s[r]  += __shfl_xor(s[r],  m, 64);
                ss[r] += __shfl_xor(ss[r], m, 64);
            }
#pragma unroll
        for (int r = 0; r < 4; ++r) {
            float mean = s[r] * (1.0f / 256.0f);
            float var  = fmaxf(ss[r] * (1.0f / 256.0f) - mean * mean, 0.0f);
            s[r] = mean; ss[r] = rsqrtf(var + 1e-5f);
        }
#pragma unroll
        for (int nt = 0; nt < 16; ++nt) {
            float gg = b2f(ws[OFF_G2 + nt * 16 + c]);
            float bb = b2f(ws[OFF_BE2 + nt * 16 + c]);
#pragma unroll
            for (int r = 0; r < 4; ++r) {
                float y = (acc2[nt][r] - s[r]) * ss[r] * gg + bb;
                Hs[(rb + q * 4 + r) * HPAD + nt * 16 + c] = (short)f2b(fmaxf(y, 0.0f));
            }
        }
    }
    __syncthreads();

    // ===== GEMM3: [16x256] @ W3^T -> [16x64], +b3, softmax =====
    f4v acc3[4];
#pragma unroll
    for (int nt = 0; nt < 4; ++nt) acc3[nt] = (f4v){0.f, 0.f, 0.f, 0.f};
#pragma unroll
    for (int ks = 0; ks < 8; ++ks) {
        s8v af = *(const s8v*)&Hs[(rb + c) * HPAD + ks * 32 + q * 8];
#pragma unroll
        for (int nt = 0; nt < 4; ++nt) {
            s8v bf_ = *(const s8v*)(ws + OFF_W3F + ((nt * 8 + ks) * 64 + l) * 8);
            acc3[nt] = __builtin_amdgcn_mfma_f32_16x16x32_bf16(af, bf_, acc3[nt], 0, 0, 0);
        }
    }
    __syncthreads();   // all Hs reads done before Ps (overlaid) is written
    {
        float mx[4] = {-1e30f, -1e30f, -1e30f, -1e30f};
#pragma unroll
        for (int nt = 0; nt < 4; ++nt) {
            float bias = b2f(ws[OFF_B3 + nt * 16 + c]);
#pragma unroll
            for (int r = 0; r < 4; ++r) {
                float v = acc3[nt][r] + bias;
                acc3[nt][r] = v;
                mx[r] = fmaxf(mx[r], v);
            }
        }
#pragma unroll
        for (int m = 1; m <= 8; m <<= 1)
#pragma unroll
            for (int r = 0; r < 4; ++r)
                mx[r] = fmaxf(mx[r], __shfl_xor(mx[r], m, 64));
        float sum[4] = {0, 0, 0, 0};
#pragma unroll
        for (int nt = 0; nt < 4; ++nt)
#pragma unroll
            for (int r = 0; r < 4; ++r) {
                float e = __expf(acc3[nt][r] - mx[r]);
                acc3[nt][r] = e;
                sum[r] += e;
            }
#pragma unroll
        for (int m = 1; m <= 8; m <<= 1)
#pragma unroll
            for (int r = 0; r < 4; ++r)
                sum[r] += __shfl_xor(sum[r], m, 64);
#pragma unroll
        for (int r = 0; r < 4; ++r) sum[r] = 1.0f / sum[r];
#pragma unroll
        for (int nt = 0; nt < 4; ++nt)
#pragma unroll
            for (int r = 0; r < 4; ++r)
                Ps[(rb + q * 4 + r) * PPAD + nt * 16 + c] = acc3[nt][r] * sum[r];
    }
    __syncthreads();   // Ps visible before Toeplitz reads

    // ===== Toeplitz: out[m,i] = sum_{s<=i} p[m,s]*a[m,i-s], DPP wave_shr =====
    // r starts as a[i]; step s: acc += p[s]*r; r = wave_shr(r) (0-fill -> causal
    // mask is free).  Rows (m, m+8) packed in __half2.
#pragma unroll 2
    for (int j = 0; j < 8; ++j) {
        const int m0 = rb + j, m1 = rb + j + 8;
        __half2 pph = __floats2half2_rn(Ps[m0 * PPAD + l], Ps[m1 * PPAD + l]);
        const int ppi = h2i(pph);
        __half2 aah = __floats2half2_rn(loadS<BF16>(a_bits, (grow0 + m0) * 64 + l),
                                        loadS<BF16>(a_bits, (grow0 + m1) * 64 + l));
        int r = h2i(aah);
        __half2 acc = __float2half2_rn(0.0f);
#pragma unroll
        for (int s = 0; s < 64; ++s) {
            const int spi = __builtin_amdgcn_readlane(ppi, s);
            acc = __hfma2(i2h(spi), i2h(r), acc);
            if (s < 63)
                r = __builtin_amdgcn_update_dpp(0, r, 0x138, 0xF, 0xF, true); // wave_shr:1, 0-fill
        }
        storeO<BF16>(out, (grow0 + m0) * 64 + l, __low2float(acc));
        storeO<BF16>(out, (grow0 + m1) * 64 + l, __high2float(acc));
    }
}

__global__ __launch_bounds__(256, 2) void shiftdec_kernel(
    const void* __restrict__ a_bits, const void* __restrict__ shifts,
    const unsigned short* __restrict__ ws, void* __restrict__ out)
{
    __shared__ __align__(16) char smem[64 * HPAD * 2];   // 33792 B; Ps overlays Hs
    short* Hs = (short*)smem;
    float* Ps = (float*)smem;                            // 64*68*4 = 17408 B <= 33792

    if (probe_bf16(a_bits))
        pipeline<true>(a_bits, shifts, ws, out, Hs, Ps);
    else
        pipeline<false>(a_bits, shifts, ws, out, Hs, Ps);
}

extern "C" void kernel_launch(void* const* d_in, const int* in_sizes, int n_in,
                              void* d_out, int out_size, void* d_ws, size_t ws_size,
                              hipStream_t stream) {
    const int B = in_sizes[0] / 64;      // rows (32768)
    const int grid = B / 64;             // 64 rows per block

    hipLaunchKernelGGL(convert_kernel, dim3(49), dim3(256), 0, stream,
                       d_in[0], d_in[2], d_in[6], d_in[10],
                       d_in[3], d_in[4], d_in[5], d_in[7], d_in[8], d_in[9], d_in[11],
                       (unsigned short*)d_ws);
    hipLaunchKernelGGL(shiftdec_kernel, dim3(grid), dim3(256), 0, stream,
                       d_in[0], d_in[1], (const unsigned short*)d_ws, d_out);
}

// Round 5
// 117.499 us; speedup vs baseline: 1.6619x; 1.2305x over previous
//
#include <hip/hip_runtime.h>
#include <hip/hip_fp16.h>

// ShiftDecoderNet fused kernel for MI355X (gfx950).  R5.
// R4: 80us kernel, all pipes idle, occupancy grid-capped at 2 blocks/CU (25%).
// R5: N-split waves. Block = 2 row-bands x 2 N-halves, 32 rows/block,
// 1024 blocks -> 4 blocks/CU -> 16 waves/CU (2x occupancy). LN stats combined
// across the half-pair via small LDS buffer. GEMM3 duplicated per half
// (softmax stays wave-local). Toeplitz split 4 j's per wave.
//
// GEMMs: mfma_f32_16x16x32_bf16.  A-frag: m=lane&15, k=(lane>>4)*8+j.
// C/D: col=lane&15, row=(lane>>4)*4+reg  (verified layouts).

typedef short s8v __attribute__((ext_vector_type(8)));   // 8 bf16 payloads
typedef float f4v __attribute__((ext_vector_type(4)));

#define HPAD 264   // short elements; row stride 528B breaks pow2 bank conflicts
#define PPAD 68    // float elements

// d_ws layout (bf16 elements)
#define OFF_W1F 0        // 16nt x 2kc x 64lane x 8  = 16384
#define OFF_W2F 16384    // 16nt x 8kc x 64lane x 8  = 65536
#define OFF_W3F 81920    //  4nt x 8kc x 64lane x 8  = 16384
#define OFF_B1  98304
#define OFF_G1  98560
#define OFF_BE1 98816
#define OFF_B2  99072
#define OFF_G2  99328
#define OFF_BE2 99584
#define OFF_B3  99840    // 64

__device__ __forceinline__ float b2f(unsigned short u) {
    union { unsigned int i; float f; } v; v.i = ((unsigned int)u) << 16; return v.f;
}
__device__ __forceinline__ unsigned short f2b(float f) {
    union { float f; unsigned int i; } v; v.f = f;
    return (unsigned short)((v.i + 0x7fffu + ((v.i >> 16) & 1u)) >> 16);  // RNE
}
__device__ __forceinline__ int h2i(__half2 h) { union { __half2 h; int i; } u; u.h = h; return u.i; }
__device__ __forceinline__ __half2 i2h(int i) { union { __half2 h; int i; } u; u.i = i; return u.h; }

__device__ __forceinline__ bool probe_bf16(const void* a_bits) {
    // a_bits is exactly {0.0,1.0}. f32 dwords: {0x0,0x3F800000} (low half 0).
    // packed-bf16 dwords: low half 0x3F80 w.p. 1/2 per word.
    unsigned int wv = ((const unsigned int*)a_bits)[threadIdx.x & 63];
    return __ballot((wv & 0xffffu) == 0x3f80u) != 0ULL;
}

// ============ kernel 0: convert + swizzle weights into d_ws (bf16) ============
__global__ __launch_bounds__(256) void convert_kernel(
    const void* __restrict__ a_probe,
    const void* __restrict__ W1, const void* __restrict__ W2, const void* __restrict__ W3,
    const void* __restrict__ b1, const void* __restrict__ g1, const void* __restrict__ be1,
    const void* __restrict__ b2, const void* __restrict__ g2, const void* __restrict__ be2,
    const void* __restrict__ b3,
    unsigned short* __restrict__ ws)
{
    const bool isbf = probe_bf16(a_probe);
    const int t = blockIdx.x * 256 + threadIdx.x;

    if (t < 12288) {            // weight 8-element chunks, frag order
        const void* W; int K, idx, dstbase;
        if (t < 2048)       { idx = t;         W = W1; K = 64;  dstbase = OFF_W1F + idx * 8; }
        else if (t < 10240) { idx = t - 2048;  W = W2; K = 256; dstbase = OFF_W2F + idx * 8; }
        else                { idx = t - 10240; W = W3; K = 256; dstbase = OFF_W3F + idx * 8; }
        int nt, kc, lane;
        if (t < 2048) { nt = idx >> 7; kc = (idx >> 6) & 1; lane = idx & 63; }
        else          { nt = idx >> 9; kc = (idx >> 6) & 7; lane = idx & 63; }
        const int row = nt * 16 + (lane & 15);
        const int col = kc * 32 + (lane >> 4) * 8;
        const int src = row * K + col;
        s8v o;
        if (isbf) {
            o = *(const s8v*)((const unsigned short*)W + src);
        } else {
            const float* f = (const float*)W + src;
#pragma unroll
            for (int j = 0; j < 8; ++j) o[j] = (short)f2b(f[j]);
        }
        *(s8v*)(ws + dstbase) = o;
    } else if (t < 12488) {     // bias/gamma/beta 8-element chunks
        const int v = t - 12288;
        const void* srcp; int base, off;
        if (v < 32)       { srcp = b1;  base = OFF_B1;  off = v * 8; }
        else if (v < 64)  { srcp = g1;  base = OFF_G1;  off = (v - 32) * 8; }
        else if (v < 96)  { srcp = be1; base = OFF_BE1; off = (v - 64) * 8; }
        else if (v < 128) { srcp = b2;  base = OFF_B2;  off = (v - 96) * 8; }
        else if (v < 160) { srcp = g2;  base = OFF_G2;  off = (v - 128) * 8; }
        else if (v < 192) { srcp = be2; base = OFF_BE2; off = (v - 160) * 8; }
        else              { srcp = b3;  base = OFF_B3;  off = (v - 192) * 8; }
#pragma unroll
        for (int j = 0; j < 8; ++j)
            ws[base + off + j] = isbf ? ((const unsigned short*)srcp)[off + j]
                                      : f2b(((const float*)srcp)[off + j]);
    }
}

// ======================= main fused pipeline ==================================
template<bool BF16>
__device__ __forceinline__ float loadS(const void* p, int idx) {
    if constexpr (BF16) return b2f(((const unsigned short*)p)[idx]);
    else return ((const float*)p)[idx];
}
template<bool BF16>
__device__ __forceinline__ s8v loadA8(const void* p, int idx) {   // activations
    if constexpr (BF16) {
        return *(const s8v*)((const unsigned short*)p + idx);
    } else {
        const float* f = (const float*)p + idx;
        f4v a = *(const f4v*)f;
        f4v b = *(const f4v*)(f + 4);
        s8v r;
#pragma unroll
        for (int i = 0; i < 4; ++i) { r[i] = (short)f2b(a[i]); r[4 + i] = (short)f2b(b[i]); }
        return r;
    }
}
template<bool BF16>
__device__ __forceinline__ void storeO(void* p, int idx, float v) {
    if constexpr (BF16) ((unsigned short*)p)[idx] = f2b(v);
    else ((float*)p)[idx] = v;
}

template<bool BF16>
__device__ __forceinline__ void pipeline(
    const void* a_bits, const void* shifts, const unsigned short* ws, void* out,
    short* Hs, float* Ps, float* SS)
{
    const int tid = threadIdx.x;
    const int w = tid >> 6;
    const int band = w >> 1;       // row-band 0,1 (16 rows each)
    const int h = w & 1;           // N-half 0,1
    const int l = tid & 63;
    const int q = l >> 4;
    const int c = l & 15;
    const int rb = band << 4;
    const int ntb = h << 3;        // this wave's first nt (0 or 8)
    const int grow0 = (int)blockIdx.x << 5;   // 32 rows/block
    // SS stat buffer: [band][half][row16][{s,ss}]
    float* myS = SS + ((band * 2 + h) * 16) * 2;
    float* otS = SS + ((band * 2 + (1 - h)) * 16) * 2;

    // ===== GEMM1: [16x64] @ W1^T -> rows band, cols [ntb*16, ntb*16+128) =====
    f4v acc1[8];
#pragma unroll
    for (int i = 0; i < 8; ++i) acc1[i] = (f4v){0.f, 0.f, 0.f, 0.f};

    const s8v xa0 = loadA8<BF16>(shifts, (grow0 + rb + c) * 64 + q * 8);
    const s8v xa1 = loadA8<BF16>(shifts, (grow0 + rb + c) * 64 + 32 + q * 8);
#pragma unroll
    for (int i = 0; i < 8; ++i) {
        const int nt = ntb + i;
        s8v wb0 = *(const s8v*)(ws + OFF_W1F + ((nt * 2 + 0) * 64 + l) * 8);
        s8v wb1 = *(const s8v*)(ws + OFF_W1F + ((nt * 2 + 1) * 64 + l) * 8);
        acc1[i] = __builtin_amdgcn_mfma_f32_16x16x32_bf16(xa0, wb0, acc1[i], 0, 0, 0);
        acc1[i] = __builtin_amdgcn_mfma_f32_16x16x32_bf16(xa1, wb1, acc1[i], 0, 0, 0);
    }
    {
        float s[4] = {0, 0, 0, 0}, ss[4] = {0, 0, 0, 0};
#pragma unroll
        for (int i = 0; i < 8; ++i) {
            float bias = b2f(ws[OFF_B1 + (ntb + i) * 16 + c]);
#pragma unroll
            for (int r = 0; r < 4; ++r) {
                float v = acc1[i][r] + bias;
                acc1[i][r] = v;
                s[r] += v; ss[r] += v * v;
            }
        }
#pragma unroll
        for (int m = 1; m <= 8; m <<= 1)
#pragma unroll
            for (int r = 0; r < 4; ++r) {
                s[r]  += __shfl_xor(s[r],  m, 64);
                ss[r] += __shfl_xor(ss[r], m, 64);
            }
        if (c == 0)
#pragma unroll
            for (int r = 0; r < 4; ++r) {
                myS[(q * 4 + r) * 2 + 0] = s[r];
                myS[(q * 4 + r) * 2 + 1] = ss[r];
            }
        __syncthreads();
#pragma unroll
        for (int r = 0; r < 4; ++r) {
            float st = s[r] + otS[(q * 4 + r) * 2 + 0];
            float sq = ss[r] + otS[(q * 4 + r) * 2 + 1];
            float mean = st * (1.0f / 256.0f);
            float var  = fmaxf(sq * (1.0f / 256.0f) - mean * mean, 0.0f);
            s[r] = mean; ss[r] = rsqrtf(var + 1e-5f);
        }
#pragma unroll
        for (int i = 0; i < 8; ++i) {
            const int nt = ntb + i;
            float gg = b2f(ws[OFF_G1 + nt * 16 + c]);
            float bb = b2f(ws[OFF_BE1 + nt * 16 + c]);
#pragma unroll
            for (int r = 0; r < 4; ++r) {
                float y = (acc1[i][r] - s[r]) * ss[r] * gg + bb;
                Hs[(rb + q * 4 + r) * HPAD + nt * 16 + c] = (short)f2b(fmaxf(y, 0.0f));
            }
        }
    }
    __syncthreads();   // full Hs band rows visible

    // ===== GEMM2: [16x256] @ W2^T -> cols [ntb*16, +128) =====
    f4v acc2[8];
#pragma unroll
    for (int i = 0; i < 8; ++i) acc2[i] = (f4v){0.f, 0.f, 0.f, 0.f};
#pragma unroll
    for (int ks = 0; ks < 8; ++ks) {
        s8v af = *(const s8v*)&Hs[(rb + c) * HPAD + ks * 32 + q * 8];
#pragma unroll
        for (int i = 0; i < 8; ++i) {
            const int nt = ntb + i;
            s8v bf_ = *(const s8v*)(ws + OFF_W2F + ((nt * 8 + ks) * 64 + l) * 8);
            acc2[i] = __builtin_amdgcn_mfma_f32_16x16x32_bf16(af, bf_, acc2[i], 0, 0, 0);
        }
    }
    {
        float s[4] = {0, 0, 0, 0}, ss[4] = {0, 0, 0, 0};
#pragma unroll
        for (int i = 0; i < 8; ++i) {
            float bias = b2f(ws[OFF_B2 + (ntb + i) * 16 + c]);
#pragma unroll
            for (int r = 0; r < 4; ++r) {
                float v = acc2[i][r] + bias;
                acc2[i][r] = v;
                s[r] += v; ss[r] += v * v;
            }
        }
#pragma unroll
        for (int m = 1; m <= 8; m <<= 1)
#pragma unroll
            for (int r = 0; r < 4; ++r) {
                s[r]  += __shfl_xor(s[r],  m, 64);
                ss[r] += __shfl_xor(ss[r], m, 64);
            }
        if (c == 0)
#pragma unroll
            for (int r = 0; r < 4; ++r) {
                myS[(q * 4 + r) * 2 + 0] = s[r];
                myS[(q * 4 + r) * 2 + 1] = ss[r];
            }
        __syncthreads();   // also separates GEMM2 Hs reads from LN2 Hs writes
#pragma unroll
        for (int r = 0; r < 4; ++r) {
            float st = s[r] + otS[(q * 4 + r) * 2 + 0];
            float sq = ss[r] + otS[(q * 4 + r) * 2 + 1];
            float mean = st * (1.0f / 256.0f);
            float var  = fmaxf(sq * (1.0f / 256.0f) - mean * mean, 0.0f);
            s[r] = mean; ss[r] = rsqrtf(var + 1e-5f);
        }
#pragma unroll
        for (int i = 0; i < 8; ++i) {
            const int nt = ntb + i;
            float gg = b2f(ws[OFF_G2 + nt * 16 + c]);
            float bb = b2f(ws[OFF_BE2 + nt * 16 + c]);
#pragma unroll
            for (int r = 0; r < 4; ++r) {
                float y = (acc2[i][r] - s[r]) * ss[r] * gg + bb;
                Hs[(rb + q * 4 + r) * HPAD + nt * 16 + c] = (short)f2b(fmaxf(y, 0.0f));
            }
        }
    }
    __syncthreads();

    // ===== GEMM3 (duplicated per half): [16x256] @ W3^T -> 64, +b3, softmax =====
    f4v acc3[4];
#pragma unroll
    for (int nt = 0; nt < 4; ++nt) acc3[nt] = (f4v){0.f, 0.f, 0.f, 0.f};
#pragma unroll
    for (int ks = 0; ks < 8; ++ks) {
        s8v af = *(const s8v*)&Hs[(rb + c) * HPAD + ks * 32 + q * 8];
#pragma unroll
        for (int nt = 0; nt < 4; ++nt) {
            s8v bf_ = *(const s8v*)(ws + OFF_W3F + ((nt * 8 + ks) * 64 + l) * 8);
            acc3[nt] = __builtin_amdgcn_mfma_f32_16x16x32_bf16(af, bf_, acc3[nt], 0, 0, 0);
        }
    }
    __syncthreads();   // ALL Hs reads done before Ps (overlaid) writes
    {
        float mx[4] = {-1e30f, -1e30f, -1e30f, -1e30f};
#pragma unroll
        for (int nt = 0; nt < 4; ++nt) {
            float bias = b2f(ws[OFF_B3 + nt * 16 + c]);
#pragma unroll
            for (int r = 0; r < 4; ++r) {
                float v = acc3[nt][r] + bias;
                acc3[nt][r] = v;
                mx[r] = fmaxf(mx[r], v);
            }
        }
#pragma unroll
        for (int m = 1; m <= 8; m <<= 1)
#pragma unroll
            for (int r = 0; r < 4; ++r)
                mx[r] = fmaxf(mx[r], __shfl_xor(mx[r], m, 64));
        float sum[4] = {0, 0, 0, 0};
#pragma unroll
        for (int nt = 0; nt < 4; ++nt)
#pragma unroll
            for (int r = 0; r < 4; ++r) {
                float e = __expf(acc3[nt][r] - mx[r]);
                acc3[nt][r] = e;
                sum[r] += e;
            }
#pragma unroll
        for (int m = 1; m <= 8; m <<= 1)
#pragma unroll
            for (int r = 0; r < 4; ++r)
                sum[r] += __shfl_xor(sum[r], m, 64);
#pragma unroll
        for (int r = 0; r < 4; ++r) sum[r] = 1.0f / sum[r];
        if (h == 0)   // halves hold identical values; one writer is enough
#pragma unroll
            for (int nt = 0; nt < 4; ++nt)
#pragma unroll
                for (int r = 0; r < 4; ++r)
                    Ps[(rb + q * 4 + r) * PPAD + nt * 16 + c] = acc3[nt][r] * sum[r];
    }
    __syncthreads();   // Ps visible

    // ===== Toeplitz: out[m,i] = sum_{s<=i} p[m,s]*a[m,i-s], DPP wave_shr =====
    // 4 j's per wave (split by half). r starts as a[i]; step s: acc += p[s]*r;
    // r = wave_shr(r) (0-fill -> causal mask free). Rows (m, m+8) in __half2.
#pragma unroll 2
    for (int jj = 0; jj < 4; ++jj) {
        const int j = h * 4 + jj;
        const int m0 = rb + j, m1 = rb + j + 8;
        __half2 pph = __floats2half2_rn(Ps[m0 * PPAD + l], Ps[m1 * PPAD + l]);
        const int ppi = h2i(pph);
        __half2 aah = __floats2half2_rn(loadS<BF16>(a_bits, (grow0 + m0) * 64 + l),
                                        loadS<BF16>(a_bits, (grow0 + m1) * 64 + l));
        int r = h2i(aah);
        __half2 acc = __float2half2_rn(0.0f);
#pragma unroll
        for (int s = 0; s < 64; ++s) {
            const int spi = __builtin_amdgcn_readlane(ppi, s);
            acc = __hfma2(i2h(spi), i2h(r), acc);
            if (s < 63)
                r = __builtin_amdgcn_update_dpp(0, r, 0x138, 0xF, 0xF, true); // wave_shr:1
        }
        storeO<BF16>(out, (grow0 + m0) * 64 + l, __low2float(acc));
        storeO<BF16>(out, (grow0 + m1) * 64 + l, __high2float(acc));
    }
}

__global__ __launch_bounds__(256, 4) void shiftdec_kernel(
    const void* __restrict__ a_bits, const void* __restrict__ shifts,
    const unsigned short* __restrict__ ws, void* __restrict__ out)
{
    __shared__ __align__(16) char smem[32 * HPAD * 2];   // 16896 B; Ps overlays Hs
    __shared__ __align__(16) float SSb[2 * 2 * 16 * 2];  // 512 B LN-stat exchange
    short* Hs = (short*)smem;
    float* Ps = (float*)smem;                            // 32*68*4 = 8704 B <= 16896

    if (probe_bf16(a_bits))
        pipeline<true>(a_bits, shifts, ws, out, Hs, Ps, SSb);
    else
        pipeline<false>(a_bits, shifts, ws, out, Hs, Ps, SSb);
}

extern "C" void kernel_launch(void* const* d_in, const int* in_sizes, int n_in,
                              void* d_out, int out_size, void* d_ws, size_t ws_size,
                              hipStream_t stream) {
    const int B = in_sizes[0] / 64;      // rows (32768)
    const int grid = B / 32;             // 32 rows per block -> 1024 blocks

    hipLaunchKernelGGL(convert_kernel, dim3(49), dim3(256), 0, stream,
                       d_in[0], d_in[2], d_in[6], d_in[10],
                       d_in[3], d_in[4], d_in[5], d_in[7], d_in[8], d_in[9], d_in[11],
                       (unsigned short*)d_ws);
    hipLaunchKernelGGL(shiftdec_kernel, dim3(grid), dim3(256), 0, stream,
                       d_in[0], d_in[1], (const unsigned short*)d_ws, d_out);
}

// Round 6
// 116.620 us; speedup vs baseline: 1.6744x; 1.0075x over previous
//
#include <hip/hip_runtime.h>
#include <hip/hip_fp16.h>

// ShiftDecoderNet fused kernel for MI355X (gfx950).  R6.
// R5: 42.8us, occupancy grid-capped at 4 blocks/CU (16 waves/CU). Pipes idle.
// R6: 4-way N-split. 16 rows/block, 2048 blocks -> 8 blocks/CU -> 32 waves/CU
// (100% structural). GEMM3 split 1 tile/wave (was duplicated 4x); softmax
// row-stats combined cross-wave via LDS (slot0=max, slot1=sum; 2 barriers).
// LN stats likewise. 7 barriers total. Toeplitz 2 j-pairs/wave.
//
// GEMMs: mfma_f32_16x16x32_bf16.  A-frag: m=lane&15, k=(lane>>4)*8+j.
// C/D: col=lane&15, row=(lane>>4)*4+reg  (verified layouts).

typedef short s8v __attribute__((ext_vector_type(8)));   // 8 bf16 payloads
typedef float f4v __attribute__((ext_vector_type(4)));

#define HPAD 264   // short elements; row stride 528B breaks pow2 bank conflicts
#define PPAD 68    // float elements

// d_ws layout (bf16 elements)
#define OFF_W1F 0        // 16nt x 2kc x 64lane x 8  = 16384
#define OFF_W2F 16384    // 16nt x 8kc x 64lane x 8  = 65536
#define OFF_W3F 81920    //  4nt x 8kc x 64lane x 8  = 16384
#define OFF_B1  98304
#define OFF_G1  98560
#define OFF_BE1 98816
#define OFF_B2  99072
#define OFF_G2  99328
#define OFF_BE2 99584
#define OFF_B3  99840    // 64

__device__ __forceinline__ float b2f(unsigned short u) {
    union { unsigned int i; float f; } v; v.i = ((unsigned int)u) << 16; return v.f;
}
__device__ __forceinline__ unsigned short f2b(float f) {
    union { float f; unsigned int i; } v; v.f = f;
    return (unsigned short)((v.i + 0x7fffu + ((v.i >> 16) & 1u)) >> 16);  // RNE
}
__device__ __forceinline__ int h2i(__half2 h) { union { __half2 h; int i; } u; u.h = h; return u.i; }
__device__ __forceinline__ __half2 i2h(int i) { union { __half2 h; int i; } u; u.i = i; return u.h; }

__device__ __forceinline__ bool probe_bf16(const void* a_bits) {
    // a_bits is exactly {0.0,1.0}. f32 dwords: {0x0,0x3F800000} (low half 0).
    // packed-bf16 dwords: low half 0x3F80 w.p. 1/2 per word.
    unsigned int wv = ((const unsigned int*)a_bits)[threadIdx.x & 63];
    return __ballot((wv & 0xffffu) == 0x3f80u) != 0ULL;
}

// ============ kernel 0: convert + swizzle weights into d_ws (bf16) ============
__global__ __launch_bounds__(256) void convert_kernel(
    const void* __restrict__ a_probe,
    const void* __restrict__ W1, const void* __restrict__ W2, const void* __restrict__ W3,
    const void* __restrict__ b1, const void* __restrict__ g1, const void* __restrict__ be1,
    const void* __restrict__ b2, const void* __restrict__ g2, const void* __restrict__ be2,
    const void* __restrict__ b3,
    unsigned short* __restrict__ ws)
{
    const bool isbf = probe_bf16(a_probe);
    const int t = blockIdx.x * 256 + threadIdx.x;

    if (t < 12288) {            // weight 8-element chunks, frag order
        const void* W; int K, idx, dstbase;
        if (t < 2048)       { idx = t;         W = W1; K = 64;  dstbase = OFF_W1F + idx * 8; }
        else if (t < 10240) { idx = t - 2048;  W = W2; K = 256; dstbase = OFF_W2F + idx * 8; }
        else                { idx = t - 10240; W = W3; K = 256; dstbase = OFF_W3F + idx * 8; }
        int nt, kc, lane;
        if (t < 2048) { nt = idx >> 7; kc = (idx >> 6) & 1; lane = idx & 63; }
        else          { nt = idx >> 9; kc = (idx >> 6) & 7; lane = idx & 63; }
        const int row = nt * 16 + (lane & 15);
        const int col = kc * 32 + (lane >> 4) * 8;
        const int src = row * K + col;
        s8v o;
        if (isbf) {
            o = *(const s8v*)((const unsigned short*)W + src);
        } else {
            const float* f = (const float*)W + src;
#pragma unroll
            for (int j = 0; j < 8; ++j) o[j] = (short)f2b(f[j]);
        }
        *(s8v*)(ws + dstbase) = o;
    } else if (t < 12488) {     // bias/gamma/beta 8-element chunks
        const int v = t - 12288;
        const void* srcp; int base, off;
        if (v < 32)       { srcp = b1;  base = OFF_B1;  off = v * 8; }
        else if (v < 64)  { srcp = g1;  base = OFF_G1;  off = (v - 32) * 8; }
        else if (v < 96)  { srcp = be1; base = OFF_BE1; off = (v - 64) * 8; }
        else if (v < 128) { srcp = b2;  base = OFF_B2;  off = (v - 96) * 8; }
        else if (v < 160) { srcp = g2;  base = OFF_G2;  off = (v - 128) * 8; }
        else if (v < 192) { srcp = be2; base = OFF_BE2; off = (v - 160) * 8; }
        else              { srcp = b3;  base = OFF_B3;  off = (v - 192) * 8; }
#pragma unroll
        for (int j = 0; j < 8; ++j)
            ws[base + off + j] = isbf ? ((const unsigned short*)srcp)[off + j]
                                      : f2b(((const float*)srcp)[off + j]);
    }
}

// ======================= main fused pipeline ==================================
template<bool BF16>
__device__ __forceinline__ float loadS(const void* p, int idx) {
    if constexpr (BF16) return b2f(((const unsigned short*)p)[idx]);
    else return ((const float*)p)[idx];
}
template<bool BF16>
__device__ __forceinline__ s8v loadA8(const void* p, int idx) {   // activations
    if constexpr (BF16) {
        return *(const s8v*)((const unsigned short*)p + idx);
    } else {
        const float* f = (const float*)p + idx;
        f4v a = *(const f4v*)f;
        f4v b = *(const f4v*)(f + 4);
        s8v r;
#pragma unroll
        for (int i = 0; i < 4; ++i) { r[i] = (short)f2b(a[i]); r[4 + i] = (short)f2b(b[i]); }
        return r;
    }
}
template<bool BF16>
__device__ __forceinline__ void storeO(void* p, int idx, float v) {
    if constexpr (BF16) ((unsigned short*)p)[idx] = f2b(v);
    else ((float*)p)[idx] = v;
}

template<bool BF16>
__device__ __forceinline__ void pipeline(
    const void* a_bits, const void* shifts, const unsigned short* ws, void* out,
    short* Hs, float* Ps, float* SS)
{
    const int tid = threadIdx.x;
    const int h = tid >> 6;        // wave = N-quarter 0..3
    const int l = tid & 63;
    const int q = l >> 4;
    const int c = l & 15;
    const int ntb = h << 2;        // first nt of this wave's quarter
    const int grow0 = (int)blockIdx.x << 4;   // 16 rows/block
    const int row = q * 4;         // +r = this lane's C/D rows

    // ===== GEMM1: [16x64] @ W1^T -> cols [ntb*16, +64) =====
    f4v acc1[4];
#pragma unroll
    for (int i = 0; i < 4; ++i) acc1[i] = (f4v){0.f, 0.f, 0.f, 0.f};

    const s8v xa0 = loadA8<BF16>(shifts, (grow0 + c) * 64 + q * 8);
    const s8v xa1 = loadA8<BF16>(shifts, (grow0 + c) * 64 + 32 + q * 8);
#pragma unroll
    for (int i = 0; i < 4; ++i) {
        const int nt = ntb + i;
        s8v wb0 = *(const s8v*)(ws + OFF_W1F + ((nt * 2 + 0) * 64 + l) * 8);
        s8v wb1 = *(const s8v*)(ws + OFF_W1F + ((nt * 2 + 1) * 64 + l) * 8);
        acc1[i] = __builtin_amdgcn_mfma_f32_16x16x32_bf16(xa0, wb0, acc1[i], 0, 0, 0);
        acc1[i] = __builtin_amdgcn_mfma_f32_16x16x32_bf16(xa1, wb1, acc1[i], 0, 0, 0);
    }
    {
        float s[4] = {0, 0, 0, 0}, ss[4] = {0, 0, 0, 0};
#pragma unroll
        for (int i = 0; i < 4; ++i) {
            float bias = b2f(ws[OFF_B1 + (ntb + i) * 16 + c]);
#pragma unroll
            for (int r = 0; r < 4; ++r) {
                float v = acc1[i][r] + bias;
                acc1[i][r] = v;
                s[r] += v; ss[r] += v * v;
            }
        }
#pragma unroll
        for (int m = 1; m <= 8; m <<= 1)
#pragma unroll
            for (int r = 0; r < 4; ++r) {
                s[r]  += __shfl_xor(s[r],  m, 64);
                ss[r] += __shfl_xor(ss[r], m, 64);
            }
        if (c == 0)
#pragma unroll
            for (int r = 0; r < 4; ++r) {
                SS[(h * 16 + row + r) * 2 + 0] = s[r];
                SS[(h * 16 + row + r) * 2 + 1] = ss[r];
            }
        __syncthreads();   // bar1: LN1 stats
#pragma unroll
        for (int r = 0; r < 4; ++r) {
            float st = 0.f, sq = 0.f;
#pragma unroll
            for (int wv = 0; wv < 4; ++wv) {
                st += SS[(wv * 16 + row + r) * 2 + 0];
                sq += SS[(wv * 16 + row + r) * 2 + 1];
            }
            float mean = st * (1.0f / 256.0f);
            float var  = fmaxf(sq * (1.0f / 256.0f) - mean * mean, 0.0f);
            s[r] = mean; ss[r] = rsqrtf(var + 1e-5f);
        }
#pragma unroll
        for (int i = 0; i < 4; ++i) {
            const int nt = ntb + i;
            float gg = b2f(ws[OFF_G1 + nt * 16 + c]);
            float bb = b2f(ws[OFF_BE1 + nt * 16 + c]);
#pragma unroll
            for (int r = 0; r < 4; ++r) {
                float y = (acc1[i][r] - s[r]) * ss[r] * gg + bb;
                Hs[(row + r) * HPAD + nt * 16 + c] = (short)f2b(fmaxf(y, 0.0f));
            }
        }
    }
    __syncthreads();   // bar2: Hs(v1) ready, SS(LN1) reads done

    // ===== GEMM2: [16x256] @ W2^T -> cols [ntb*16, +64) =====
    f4v acc2[4];
#pragma unroll
    for (int i = 0; i < 4; ++i) acc2[i] = (f4v){0.f, 0.f, 0.f, 0.f};
#pragma unroll
    for (int ks = 0; ks < 8; ++ks) {
        s8v af = *(const s8v*)&Hs[c * HPAD + ks * 32 + q * 8];
#pragma unroll
        for (int i = 0; i < 4; ++i) {
            const int nt = ntb + i;
            s8v bf_ = *(const s8v*)(ws + OFF_W2F + ((nt * 8 + ks) * 64 + l) * 8);
            acc2[i] = __builtin_amdgcn_mfma_f32_16x16x32_bf16(af, bf_, acc2[i], 0, 0, 0);
        }
    }
    {
        float s[4] = {0, 0, 0, 0}, ss[4] = {0, 0, 0, 0};
#pragma unroll
        for (int i = 0; i < 4; ++i) {
            float bias = b2f(ws[OFF_B2 + (ntb + i) * 16 + c]);
#pragma unroll
            for (int r = 0; r < 4; ++r) {
                float v = acc2[i][r] + bias;
                acc2[i][r] = v;
                s[r] += v; ss[r] += v * v;
            }
        }
#pragma unroll
        for (int m = 1; m <= 8; m <<= 1)
#pragma unroll
            for (int r = 0; r < 4; ++r) {
                s[r]  += __shfl_xor(s[r],  m, 64);
                ss[r] += __shfl_xor(ss[r], m, 64);
            }
        if (c == 0)
#pragma unroll
            for (int r = 0; r < 4; ++r) {
                SS[(h * 16 + row + r) * 2 + 0] = s[r];
                SS[(h * 16 + row + r) * 2 + 1] = ss[r];
            }
        __syncthreads();   // bar3: LN2 stats (all GEMM2 Hs reads also done)
#pragma unroll
        for (int r = 0; r < 4; ++r) {
            float st = 0.f, sq = 0.f;
#pragma unroll
            for (int wv = 0; wv < 4; ++wv) {
                st += SS[(wv * 16 + row + r) * 2 + 0];
                sq += SS[(wv * 16 + row + r) * 2 + 1];
            }
            float mean = st * (1.0f / 256.0f);
            float var  = fmaxf(sq * (1.0f / 256.0f) - mean * mean, 0.0f);
            s[r] = mean; ss[r] = rsqrtf(var + 1e-5f);
        }
#pragma unroll
        for (int i = 0; i < 4; ++i) {
            const int nt = ntb + i;
            float gg = b2f(ws[OFF_G2 + nt * 16 + c]);
            float bb = b2f(ws[OFF_BE2 + nt * 16 + c]);
#pragma unroll
            for (int r = 0; r < 4; ++r) {
                float y = (acc2[i][r] - s[r]) * ss[r] * gg + bb;
                Hs[(row + r) * HPAD + nt * 16 + c] = (short)f2b(fmaxf(y, 0.0f));
            }
        }
    }
    __syncthreads();   // bar4: Hs(v2) ready, SS(LN2) reads done

    // ===== GEMM3 (split): wave h computes cols [h*16, +16); softmax cross-wave =====
    f4v acc3 = (f4v){0.f, 0.f, 0.f, 0.f};
#pragma unroll
    for (int ks = 0; ks < 8; ++ks) {
        s8v af = *(const s8v*)&Hs[c * HPAD + ks * 32 + q * 8];
        s8v bf_ = *(const s8v*)(ws + OFF_W3F + ((h * 8 + ks) * 64 + l) * 8);
        acc3 = __builtin_amdgcn_mfma_f32_16x16x32_bf16(af, bf_, acc3, 0, 0, 0);
    }
    {
        float mx = -1e30f;
        const float bias = b2f(ws[OFF_B3 + h * 16 + c]);
#pragma unroll
        for (int r = 0; r < 4; ++r) {
            acc3[r] += bias;
            mx = fmaxf(mx, acc3[r]);
        }
        // per-row partial max over this wave's 16 cols: shuffle over c bits...
        // mx currently mixes 4 rows per lane; redo per-row: recompute per r.
        float mxr[4];
#pragma unroll
        for (int r = 0; r < 4; ++r) mxr[r] = acc3[r];
#pragma unroll
        for (int m = 1; m <= 8; m <<= 1)
#pragma unroll
            for (int r = 0; r < 4; ++r)
                mxr[r] = fmaxf(mxr[r], __shfl_xor(mxr[r], m, 64));
        if (c == 0)
#pragma unroll
            for (int r = 0; r < 4; ++r)
                SS[(h * 16 + row + r) * 2 + 0] = mxr[r];
        __syncthreads();   // bar5: max stats (also: all Hs reads done -> Ps overlay safe)
        float sum[4];
#pragma unroll
        for (int r = 0; r < 4; ++r) {
            float M = SS[(0 * 16 + row + r) * 2 + 0];
            M = fmaxf(M, SS[(1 * 16 + row + r) * 2 + 0]);
            M = fmaxf(M, SS[(2 * 16 + row + r) * 2 + 0]);
            M = fmaxf(M, SS[(3 * 16 + row + r) * 2 + 0]);
            float e = __expf(acc3[r] - M);
            acc3[r] = e;
            sum[r] = e;
        }
#pragma unroll
        for (int m = 1; m <= 8; m <<= 1)
#pragma unroll
            for (int r = 0; r < 4; ++r)
                sum[r] += __shfl_xor(sum[r], m, 64);
        if (c == 0)
#pragma unroll
            for (int r = 0; r < 4; ++r)
                SS[(h * 16 + row + r) * 2 + 1] = sum[r];   // slot1: no clash with pending slot0 reads
        __syncthreads();   // bar6: sum stats
#pragma unroll
        for (int r = 0; r < 4; ++r) {
            float S = SS[(0 * 16 + row + r) * 2 + 1] + SS[(1 * 16 + row + r) * 2 + 1]
                    + SS[(2 * 16 + row + r) * 2 + 1] + SS[(3 * 16 + row + r) * 2 + 1];
            Ps[(row + r) * PPAD + h * 16 + c] = acc3[r] / S;
        }
    }
    __syncthreads();   // bar7: Ps ready

    // ===== Toeplitz: out[m,i] = sum_{s<=i} p[m,s]*a[m,i-s], DPP wave_shr =====
    // 2 j-pairs per wave. r starts as a[i]; step s: acc += p[s]*r; r = wave_shr(r)
    // (0-fill -> causal mask free). Rows (m, m+8) packed in __half2.
#pragma unroll
    for (int jj = 0; jj < 2; ++jj) {
        const int j = h * 2 + jj;
        const int m0 = j, m1 = j + 8;
        __half2 pph = __floats2half2_rn(Ps[m0 * PPAD + l], Ps[m1 * PPAD + l]);
        const int ppi = h2i(pph);
        __half2 aah = __floats2half2_rn(loadS<BF16>(a_bits, (grow0 + m0) * 64 + l),
                                        loadS<BF16>(a_bits, (grow0 + m1) * 64 + l));
        int rr = h2i(aah);
        __half2 acc = __float2half2_rn(0.0f);
#pragma unroll
        for (int s = 0; s < 64; ++s) {
            const int spi = __builtin_amdgcn_readlane(ppi, s);
            acc = __hfma2(i2h(spi), i2h(rr), acc);
            if (s < 63)
                rr = __builtin_amdgcn_update_dpp(0, rr, 0x138, 0xF, 0xF, true); // wave_shr:1
        }
        storeO<BF16>(out, (grow0 + m0) * 64 + l, __low2float(acc));
        storeO<BF16>(out, (grow0 + m1) * 64 + l, __high2float(acc));
    }
}

__global__ __launch_bounds__(256, 8) void shiftdec_kernel(
    const void* __restrict__ a_bits, const void* __restrict__ shifts,
    const unsigned short* __restrict__ ws, void* __restrict__ out)
{
    __shared__ __align__(16) char smem[16 * HPAD * 2];   // 8448 B; Ps overlays Hs
    __shared__ __align__(16) float SSb[4 * 16 * 2];      // 512 B stat exchange
    short* Hs = (short*)smem;
    float* Ps = (float*)smem;                            // 16*68*4 = 4352 B <= 8448

    if (probe_bf16(a_bits))
        pipeline<true>(a_bits, shifts, ws, out, Hs, Ps, SSb);
    else
        pipeline<false>(a_bits, shifts, ws, out, Hs, Ps, SSb);
}

extern "C" void kernel_launch(void* const* d_in, const int* in_sizes, int n_in,
                              void* d_out, int out_size, void* d_ws, size_t ws_size,
                              hipStream_t stream) {
    const int B = in_sizes[0] / 64;      // rows (32768)
    const int grid = B / 16;             // 16 rows per block -> 2048 blocks

    hipLaunchKernelGGL(convert_kernel, dim3(49), dim3(256), 0, stream,
                       d_in[0], d_in[2], d_in[6], d_in[10],
                       d_in[3], d_in[4], d_in[5], d_in[7], d_in[8], d_in[9], d_in[11],
                       (unsigned short*)d_ws);
    hipLaunchKernelGGL(shiftdec_kernel, dim3(grid), dim3(256), 0, stream,
                       d_in[0], d_in[1], (const unsigned short*)d_ws, d_out);
}

// Round 7
// 115.705 us; speedup vs baseline: 1.6877x; 1.0079x over previous
//
#include <hip/hip_runtime.h>
#include <hip/hip_fp16.h>

// ShiftDecoderNet fused kernel for MI355X (gfx950).  R7.
// R6 flatlined (~40us kernel): total VALU work per SIMD is the limiter
// (VALUBusy 33% at 4200 inst/wave; occupancy doubling was a wash).
// R7 cuts total VALU: v_cvt_pk_bf16_f32 for all f32->bf16 pairs (1 inst / 2
// vals vs ~4/val), softmax max-subtraction dropped (logits bounded ~|3|,
// exp-safe; kills 1 barrier + 1 LDS stat round), rcp for 1/S. 6 barriers.
//
// GEMMs: mfma_f32_16x16x32_bf16.  A-frag: m=lane&15, k=(lane>>4)*8+j.
// C/D: col=lane&15, row=(lane>>4)*4+reg  (verified layouts).

typedef short s8v __attribute__((ext_vector_type(8)));   // 8 bf16 payloads
typedef float f4v __attribute__((ext_vector_type(4)));

#define HPAD 264   // short elements; row stride 528B breaks pow2 bank conflicts
#define PPAD 68    // float elements

// d_ws layout (bf16 elements)
#define OFF_W1F 0        // 16nt x 2kc x 64lane x 8  = 16384
#define OFF_W2F 16384    // 16nt x 8kc x 64lane x 8  = 65536
#define OFF_W3F 81920    //  4nt x 8kc x 64lane x 8  = 16384
#define OFF_B1  98304
#define OFF_G1  98560
#define OFF_BE1 98816
#define OFF_B2  99072
#define OFF_G2  99328
#define OFF_BE2 99584
#define OFF_B3  99840    // 64

__device__ __forceinline__ float b2f(unsigned short u) {
    union { unsigned int i; float f; } v; v.i = ((unsigned int)u) << 16; return v.f;
}
__device__ __forceinline__ unsigned short f2b(float f) {
    union { float f; unsigned int i; } v; v.f = f;
    return (unsigned short)((v.i + 0x7fffu + ((v.i >> 16) & 1u)) >> 16);  // RNE
}
// packed f32x2 -> bf16x2 (lo=a, hi=b), RNE. One VALU inst.
__device__ __forceinline__ unsigned int cvtpk(float a, float b) {
    unsigned int r;
    asm("v_cvt_pk_bf16_f32 %0, %1, %2" : "=v"(r) : "v"(a), "v"(b));
    return r;
}
__device__ __forceinline__ int h2i(__half2 h) { union { __half2 h; int i; } u; u.h = h; return u.i; }
__device__ __forceinline__ __half2 i2h(int i) { union { __half2 h; int i; } u; u.i = i; return u.h; }

__device__ __forceinline__ bool probe_bf16(const void* a_bits) {
    // a_bits is exactly {0.0,1.0}. f32 dwords: {0x0,0x3F800000} (low half 0).
    // packed-bf16 dwords: low half 0x3F80 w.p. 1/2 per word.
    unsigned int wv = ((const unsigned int*)a_bits)[threadIdx.x & 63];
    return __ballot((wv & 0xffffu) == 0x3f80u) != 0ULL;
}

// ============ kernel 0: convert + swizzle weights into d_ws (bf16) ============
__global__ __launch_bounds__(256) void convert_kernel(
    const void* __restrict__ a_probe,
    const void* __restrict__ W1, const void* __restrict__ W2, const void* __restrict__ W3,
    const void* __restrict__ b1, const void* __restrict__ g1, const void* __restrict__ be1,
    const void* __restrict__ b2, const void* __restrict__ g2, const void* __restrict__ be2,
    const void* __restrict__ b3,
    unsigned short* __restrict__ ws)
{
    const bool isbf = probe_bf16(a_probe);
    const int t = blockIdx.x * 256 + threadIdx.x;

    if (t < 12288) {            // weight 8-element chunks, frag order
        const void* W; int K, idx, dstbase;
        if (t < 2048)       { idx = t;         W = W1; K = 64;  dstbase = OFF_W1F + idx * 8; }
        else if (t < 10240) { idx = t - 2048;  W = W2; K = 256; dstbase = OFF_W2F + idx * 8; }
        else                { idx = t - 10240; W = W3; K = 256; dstbase = OFF_W3F + idx * 8; }
        int nt, kc, lane;
        if (t < 2048) { nt = idx >> 7; kc = (idx >> 6) & 1; lane = idx & 63; }
        else          { nt = idx >> 9; kc = (idx >> 6) & 7; lane = idx & 63; }
        const int row = nt * 16 + (lane & 15);
        const int col = kc * 32 + (lane >> 4) * 8;
        const int src = row * K + col;
        s8v o;
        if (isbf) {
            o = *(const s8v*)((const unsigned short*)W + src);
        } else {
            const float* f = (const float*)W + src;
#pragma unroll
            for (int j = 0; j < 8; ++j) o[j] = (short)f2b(f[j]);
        }
        *(s8v*)(ws + dstbase) = o;
    } else if (t < 12488) {     // bias/gamma/beta 8-element chunks
        const int v = t - 12288;
        const void* srcp; int base, off;
        if (v < 32)       { srcp = b1;  base = OFF_B1;  off = v * 8; }
        else if (v < 64)  { srcp = g1;  base = OFF_G1;  off = (v - 32) * 8; }
        else if (v < 96)  { srcp = be1; base = OFF_BE1; off = (v - 64) * 8; }
        else if (v < 128) { srcp = b2;  base = OFF_B2;  off = (v - 96) * 8; }
        else if (v < 160) { srcp = g2;  base = OFF_G2;  off = (v - 128) * 8; }
        else if (v < 192) { srcp = be2; base = OFF_BE2; off = (v - 160) * 8; }
        else              { srcp = b3;  base = OFF_B3;  off = (v - 192) * 8; }
#pragma unroll
        for (int j = 0; j < 8; ++j)
            ws[base + off + j] = isbf ? ((const unsigned short*)srcp)[off + j]
                                      : f2b(((const float*)srcp)[off + j]);
    }
}

// ======================= main fused pipeline ==================================
template<bool BF16>
__device__ __forceinline__ float loadS(const void* p, int idx) {
    if constexpr (BF16) return b2f(((const unsigned short*)p)[idx]);
    else return ((const float*)p)[idx];
}
template<bool BF16>
__device__ __forceinline__ s8v loadA8(const void* p, int idx) {   // activations
    if constexpr (BF16) {
        return *(const s8v*)((const unsigned short*)p + idx);
    } else {
        const float* f = (const float*)p + idx;
        f4v a = *(const f4v*)f;
        f4v b = *(const f4v*)(f + 4);
        union { s8v s; unsigned int u[4]; } r;
        r.u[0] = cvtpk(a[0], a[1]);
        r.u[1] = cvtpk(a[2], a[3]);
        r.u[2] = cvtpk(b[0], b[1]);
        r.u[3] = cvtpk(b[2], b[3]);
        return r.s;
    }
}
template<bool BF16>
__device__ __forceinline__ void storeO(void* p, int idx, float v) {
    if constexpr (BF16) ((unsigned short*)p)[idx] = f2b(v);
    else ((float*)p)[idx] = v;
}

template<bool BF16>
__device__ __forceinline__ void pipeline(
    const void* a_bits, const void* shifts, const unsigned short* ws, void* out,
    short* Hs, float* Ps, float* SS)
{
    const int tid = threadIdx.x;
    const int h = tid >> 6;        // wave = N-quarter 0..3
    const int l = tid & 63;
    const int q = l >> 4;
    const int c = l & 15;
    const int ntb = h << 2;        // first nt of this wave's quarter
    const int grow0 = (int)blockIdx.x << 4;   // 16 rows/block
    const int row = q * 4;         // +r = this lane's C/D rows

    // ===== GEMM1: [16x64] @ W1^T -> cols [ntb*16, +64) =====
    f4v acc1[4];
#pragma unroll
    for (int i = 0; i < 4; ++i) acc1[i] = (f4v){0.f, 0.f, 0.f, 0.f};

    const s8v xa0 = loadA8<BF16>(shifts, (grow0 + c) * 64 + q * 8);
    const s8v xa1 = loadA8<BF16>(shifts, (grow0 + c) * 64 + 32 + q * 8);
#pragma unroll
    for (int i = 0; i < 4; ++i) {
        const int nt = ntb + i;
        s8v wb0 = *(const s8v*)(ws + OFF_W1F + ((nt * 2 + 0) * 64 + l) * 8);
        s8v wb1 = *(const s8v*)(ws + OFF_W1F + ((nt * 2 + 1) * 64 + l) * 8);
        acc1[i] = __builtin_amdgcn_mfma_f32_16x16x32_bf16(xa0, wb0, acc1[i], 0, 0, 0);
        acc1[i] = __builtin_amdgcn_mfma_f32_16x16x32_bf16(xa1, wb1, acc1[i], 0, 0, 0);
    }
    {
        float s[4] = {0, 0, 0, 0}, ss[4] = {0, 0, 0, 0};
#pragma unroll
        for (int i = 0; i < 4; ++i) {
            float bias = b2f(ws[OFF_B1 + (ntb + i) * 16 + c]);
#pragma unroll
            for (int r = 0; r < 4; ++r) {
                float v = acc1[i][r] + bias;
                acc1[i][r] = v;
                s[r] += v; ss[r] += v * v;
            }
        }
#pragma unroll
        for (int m = 1; m <= 8; m <<= 1)
#pragma unroll
            for (int r = 0; r < 4; ++r) {
                s[r]  += __shfl_xor(s[r],  m, 64);
                ss[r] += __shfl_xor(ss[r], m, 64);
            }
        if (c == 0)
#pragma unroll
            for (int r = 0; r < 4; ++r) {
                SS[(h * 16 + row + r) * 2 + 0] = s[r];
                SS[(h * 16 + row + r) * 2 + 1] = ss[r];
            }
        __syncthreads();   // bar1: LN1 stats
#pragma unroll
        for (int r = 0; r < 4; ++r) {
            float st = 0.f, sq = 0.f;
#pragma unroll
            for (int wv = 0; wv < 4; ++wv) {
                st += SS[(wv * 16 + row + r) * 2 + 0];
                sq += SS[(wv * 16 + row + r) * 2 + 1];
            }
            float mean = st * (1.0f / 256.0f);
            float var  = fmaxf(sq * (1.0f / 256.0f) - mean * mean, 0.0f);
            s[r] = mean; ss[r] = rsqrtf(var + 1e-5f);
        }
#pragma unroll
        for (int i = 0; i < 4; ++i) {
            const int nt = ntb + i;
            float gg = b2f(ws[OFF_G1 + nt * 16 + c]);
            float bb = b2f(ws[OFF_BE1 + nt * 16 + c]);
            float y[4];
#pragma unroll
            for (int r = 0; r < 4; ++r)
                y[r] = fmaxf((acc1[i][r] - s[r]) * ss[r] * gg + bb, 0.0f);
            unsigned int u01 = cvtpk(y[0], y[1]);
            unsigned int u23 = cvtpk(y[2], y[3]);
            Hs[(row + 0) * HPAD + nt * 16 + c] = (short)(u01 & 0xffffu);
            Hs[(row + 1) * HPAD + nt * 16 + c] = (short)(u01 >> 16);
            Hs[(row + 2) * HPAD + nt * 16 + c] = (short)(u23 & 0xffffu);
            Hs[(row + 3) * HPAD + nt * 16 + c] = (short)(u23 >> 16);
        }
    }
    __syncthreads();   // bar2: Hs(v1) ready, SS(LN1) reads done

    // ===== GEMM2: [16x256] @ W2^T -> cols [ntb*16, +64) =====
    f4v acc2[4];
#pragma unroll
    for (int i = 0; i < 4; ++i) acc2[i] = (f4v){0.f, 0.f, 0.f, 0.f};
#pragma unroll
    for (int ks = 0; ks < 8; ++ks) {
        s8v af = *(const s8v*)&Hs[c * HPAD + ks * 32 + q * 8];
#pragma unroll
        for (int i = 0; i < 4; ++i) {
            const int nt = ntb + i;
            s8v bf_ = *(const s8v*)(ws + OFF_W2F + ((nt * 8 + ks) * 64 + l) * 8);
            acc2[i] = __builtin_amdgcn_mfma_f32_16x16x32_bf16(af, bf_, acc2[i], 0, 0, 0);
        }
    }
    {
        float s[4] = {0, 0, 0, 0}, ss[4] = {0, 0, 0, 0};
#pragma unroll
        for (int i = 0; i < 4; ++i) {
            float bias = b2f(ws[OFF_B2 + (ntb + i) * 16 + c]);
#pragma unroll
            for (int r = 0; r < 4; ++r) {
                float v = acc2[i][r] + bias;
                acc2[i][r] = v;
                s[r] += v; ss[r] += v * v;
            }
        }
#pragma unroll
        for (int m = 1; m <= 8; m <<= 1)
#pragma unroll
            for (int r = 0; r < 4; ++r) {
                s[r]  += __shfl_xor(s[r],  m, 64);
                ss[r] += __shfl_xor(ss[r], m, 64);
            }
        if (c == 0)
#pragma unroll
            for (int r = 0; r < 4; ++r) {
                SS[(h * 16 + row + r) * 2 + 0] = s[r];
                SS[(h * 16 + row + r) * 2 + 1] = ss[r];
            }
        __syncthreads();   // bar3: LN2 stats (all GEMM2 Hs reads also done)
#pragma unroll
        for (int r = 0; r < 4; ++r) {
            float st = 0.f, sq = 0.f;
#pragma unroll
            for (int wv = 0; wv < 4; ++wv) {
                st += SS[(wv * 16 + row + r) * 2 + 0];
                sq += SS[(wv * 16 + row + r) * 2 + 1];
            }
            float mean = st * (1.0f / 256.0f);
            float var  = fmaxf(sq * (1.0f / 256.0f) - mean * mean, 0.0f);
            s[r] = mean; ss[r] = rsqrtf(var + 1e-5f);
        }
#pragma unroll
        for (int i = 0; i < 4; ++i) {
            const int nt = ntb + i;
            float gg = b2f(ws[OFF_G2 + nt * 16 + c]);
            float bb = b2f(ws[OFF_BE2 + nt * 16 + c]);
            float y[4];
#pragma unroll
            for (int r = 0; r < 4; ++r)
                y[r] = fmaxf((acc2[i][r] - s[r]) * ss[r] * gg + bb, 0.0f);
            unsigned int u01 = cvtpk(y[0], y[1]);
            unsigned int u23 = cvtpk(y[2], y[3]);
            Hs[(row + 0) * HPAD + nt * 16 + c] = (short)(u01 & 0xffffu);
            Hs[(row + 1) * HPAD + nt * 16 + c] = (short)(u01 >> 16);
            Hs[(row + 2) * HPAD + nt * 16 + c] = (short)(u23 & 0xffffu);
            Hs[(row + 3) * HPAD + nt * 16 + c] = (short)(u23 >> 16);
        }
    }
    __syncthreads();   // bar4: Hs(v2) ready, SS(LN2) reads done

    // ===== GEMM3 (split): wave h computes cols [h*16, +16); softmax cross-wave ===
    // No max-subtraction: logits bounded (|x| ~< 3 post-LN), exp is safe.
    f4v acc3 = (f4v){0.f, 0.f, 0.f, 0.f};
#pragma unroll
    for (int ks = 0; ks < 8; ++ks) {
        s8v af = *(const s8v*)&Hs[c * HPAD + ks * 32 + q * 8];
        s8v bf_ = *(const s8v*)(ws + OFF_W3F + ((h * 8 + ks) * 64 + l) * 8);
        acc3 = __builtin_amdgcn_mfma_f32_16x16x32_bf16(af, bf_, acc3, 0, 0, 0);
    }
    {
        const float bias = b2f(ws[OFF_B3 + h * 16 + c]);
        float sum[4];
#pragma unroll
        for (int r = 0; r < 4; ++r) {
            float e = __expf(acc3[r] + bias);
            acc3[r] = e;
            sum[r] = e;
        }
#pragma unroll
        for (int m = 1; m <= 8; m <<= 1)
#pragma unroll
            for (int r = 0; r < 4; ++r)
                sum[r] += __shfl_xor(sum[r], m, 64);
        if (c == 0)
#pragma unroll
            for (int r = 0; r < 4; ++r)
                SS[(h * 16 + row + r) * 2 + 0] = sum[r];
        __syncthreads();   // bar5: sum stats; also all Hs reads done -> Ps overlay safe
#pragma unroll
        for (int r = 0; r < 4; ++r) {
            float S = SS[(0 * 16 + row + r) * 2 + 0] + SS[(1 * 16 + row + r) * 2 + 0]
                    + SS[(2 * 16 + row + r) * 2 + 0] + SS[(3 * 16 + row + r) * 2 + 0];
            float inv = __builtin_amdgcn_rcpf(S);   // |rel err| ~1e-7, fine at 1.5e-2 tol
            Ps[(row + r) * PPAD + h * 16 + c] = acc3[r] * inv;
        }
    }
    __syncthreads();   // bar6: Ps ready

    // ===== Toeplitz: out[m,i] = sum_{s<=i} p[m,s]*a[m,i-s], DPP wave_shr =====
    // 2 j-pairs per wave. r starts as a[i]; step s: acc += p[s]*r; r = wave_shr(r)
    // (0-fill -> causal mask free). Rows (m, m+8) packed in __half2.
#pragma unroll
    for (int jj = 0; jj < 2; ++jj) {
        const int j = h * 2 + jj;
        const int m0 = j, m1 = j + 8;
        __half2 pph = __floats2half2_rn(Ps[m0 * PPAD + l], Ps[m1 * PPAD + l]);
        const int ppi = h2i(pph);
        __half2 aah = __floats2half2_rn(loadS<BF16>(a_bits, (grow0 + m0) * 64 + l),
                                        loadS<BF16>(a_bits, (grow0 + m1) * 64 + l));
        int rr = h2i(aah);
        __half2 acc = __float2half2_rn(0.0f);
#pragma unroll
        for (int s = 0; s < 64; ++s) {
            const int spi = __builtin_amdgcn_readlane(ppi, s);
            acc = __hfma2(i2h(spi), i2h(rr), acc);
            if (s < 63)
                rr = __builtin_amdgcn_update_dpp(0, rr, 0x138, 0xF, 0xF, true); // wave_shr:1
        }
        storeO<BF16>(out, (grow0 + m0) * 64 + l, __low2float(acc));
        storeO<BF16>(out, (grow0 + m1) * 64 + l, __high2float(acc));
    }
}

__global__ __launch_bounds__(256, 8) void shiftdec_kernel(
    const void* __restrict__ a_bits, const void* __restrict__ shifts,
    const unsigned short* __restrict__ ws, void* __restrict__ out)
{
    __shared__ __align__(16) char smem[16 * HPAD * 2];   // 8448 B; Ps overlays Hs
    __shared__ __align__(16) float SSb[4 * 16 * 2];      // 512 B stat exchange
    short* Hs = (short*)smem;
    float* Ps = (float*)smem;                            // 16*68*4 = 4352 B <= 8448

    if (probe_bf16(a_bits))
        pipeline<true>(a_bits, shifts, ws, out, Hs, Ps, SSb);
    else
        pipeline<false>(a_bits, shifts, ws, out, Hs, Ps, SSb);
}

extern "C" void kernel_launch(void* const* d_in, const int* in_sizes, int n_in,
                              void* d_out, int out_size, void* d_ws, size_t ws_size,
                              hipStream_t stream) {
    const int B = in_sizes[0] / 64;      // rows (32768)
    const int grid = B / 16;             // 16 rows per block -> 2048 blocks

    hipLaunchKernelGGL(convert_kernel, dim3(49), dim3(256), 0, stream,
                       d_in[0], d_in[2], d_in[6], d_in[10],
                       d_in[3], d_in[4], d_in[5], d_in[7], d_in[8], d_in[9], d_in[11],
                       (unsigned short*)d_ws);
    hipLaunchKernelGGL(shiftdec_kernel, dim3(grid), dim3(256), 0, stream,
                       d_in[0], d_in[1], (const unsigned short*)d_ws, d_out);
}